// Round 1
// 359.600 us; speedup vs baseline: 1.3910x; 1.3910x over previous
//
#include <hip/hip_runtime.h>
#include <math.h>

// B=64, I=4096, C=32, D=d=16
#define ITILES 256
#define IPB    16

typedef __bf16 bf16x8 __attribute__((ext_vector_type(8)));
typedef float  f32x16 __attribute__((ext_vector_type(16)));

__device__ inline unsigned short f2bf(float f) {   // rne bf16 truncation
    unsigned int x = __float_as_uint(f);
    x += 0x7fff + ((x >> 16) & 1);
    return (unsigned short)(x >> 16);
}
__device__ inline float bf2f(unsigned short u) {
    return __uint_as_float(((unsigned int)u) << 16);
}
__device__ inline uint4 pack8(const unsigned short* o) {
    uint4 p;
    p.x = o[0] | ((unsigned)o[1] << 16);
    p.y = o[2] | ((unsigned)o[3] << 16);
    p.z = o[4] | ((unsigned)o[5] << 16);
    p.w = o[6] | ((unsigned)o[7] << 16);
    return p;
}

// packed rne f32 -> 2x bf16 (src0 -> [15:0], src1 -> [31:16])
__device__ inline unsigned cvtpk(float lo, float hi) {
    unsigned r;
    asm("v_cvt_pk_bf16_f32 %0, %1, %2" : "=v"(r) : "v"(lo), "v"(hi));
    return r;
}
// 3-term bf16 split of a pair of weights (same rne-at-each-level math as the
// old prep_w, just packed: returns plane-1 word, writes plane-2/3 words).
__device__ inline unsigned split3(float x, float y, unsigned& q2, unsigned& q3) {
    unsigned q1 = cvtpk(x, y);
    float f1x = __uint_as_float(q1 << 16);
    float f1y = __uint_as_float(q1 & 0xffff0000u);
    float rx = x - f1x, ry = y - f1y;          // exact (Sterbenz)
    q2 = cvtpk(rx, ry);
    float f2x = __uint_as_float(q2 << 16);
    float f2y = __uint_as_float(q2 & 0xffff0000u);
    q3 = cvtpk(rx - f2x, ry - f2y);
    return q1;
}

// ---------------------------------------------------------------------------
// prep_x: x fp32 [b][i][d] -> Xp bf16x3 in B-fragment lane order.
// B[k = (lane>>5)*8 + j][n = lane&31 (+32*ntile)].
// Xp[a*4096*1024 + i*1024 + kh*512 + b*8 + j]
// (kept: the b-major -> i-major transpose is the part the pass kernel cannot
//  do coalesced on its own; x is only 17 MB so this is ~7 us)
// ---------------------------------------------------------------------------
__global__ __launch_bounds__(128) void prep_x(const float* __restrict__ x,
                                              unsigned short* __restrict__ Xp)
{
    const int i = blockIdx.x;
    const int t = threadIdx.x;           // 128 = 64 b x 2 kh
    const int b = t >> 1, kh = t & 1;
    const float4* s4 = (const float4*)(x + ((size_t)b * 4096 + i) * 16 + kh * 8);
    float4 wa = s4[0], wb = s4[1];
    float wv[8] = {wa.x, wa.y, wa.z, wa.w, wb.x, wb.y, wb.z, wb.w};
    unsigned short o1[8], o2[8], o3[8];
    #pragma unroll
    for (int j = 0; j < 8; ++j) {
        float w = wv[j];
        o1[j] = f2bf(w);            float f1 = bf2f(o1[j]);
        o2[j] = f2bf(w - f1);       float f2 = bf2f(o2[j]);
        o3[j] = f2bf(w - f1 - f2);
    }
    unsigned short* dst = Xp + (size_t)i * 1024 + kh * 512 + b * 8;
    *(uint4*)(dst)            = pack8(o1);
    *(uint4*)(dst + 4194304)  = pack8(o2);
    *(uint4*)(dst + 8388608)  = pack8(o3);
}

// ---------------------------------------------------------------------------
// Pass kernel, MFMA edition. Grid=256 (1 block/CU), block=1024 (16 waves).
// Wave = M-tile mt (16 tiles x 32 rows = all 512 (c,D)); N = 2 tiles (64 b).
//
// NEW: no Wp intermediate. Each lane reads its 8 fp32 weights DIRECT from W
// (wave covers a contiguous 2 KB region: c = 2mt+((l31>>2)&1),
//  D = (l31&3)+4*(l31>>3), d = kh*8..+8 — every 64B line hit by exactly 2
//  lanes) and does the 3-way bf16 split in registers via v_cvt_pk_bf16_f32.
// This removes the 201 MB Wp write + 3x201 MB Wp reads; W fp32 (134 MB) is
// read once per pass and stays L3-resident for passes 2/3.
//
// 12 MFMAs emulate fp32: u = W1X1 + (W1X2+W2X1) + (W1X3+W2X2+W3X1).
// C-frag element (reg q, lane): b = 32*nt + (lane&31), c = 2mt + (lane>>5),
// D = q. Routing identical to previous version.
// ---------------------------------------------------------------------------
template<int USE_V>
__global__ __launch_bounds__(1024, 4)
void pass_kernel(const float* __restrict__ W,
                 const unsigned short* __restrict__ Xp,
                 const float* __restrict__ vg,
                 float* __restrict__ slab)
{
    __shared__ float4 vt[8192];          // 128 KB  v[b][cd] xor-swizzled
    __shared__ float  p_lds[32 * 65];    // p[c][b], pitch 65 (conflict-free both axes)
    __shared__ float  cij_lds[32 * 65];

    const int tid   = threadIdx.x;
    const int mt    = tid >> 6;          // wave index = M-tile
    const int lane  = tid & 63;
    const int l31   = lane & 31;
    const int h     = lane >> 5;
    const int cA    = 2 * mt + h;        // this lane's capsule index in C-frag
    const int itile = blockIdx.x;
    const int i0    = itile * IPB;

    // A-side fp32 source for this lane (A-frag row mapping, see header)
    const int cW = 2 * mt + ((l31 >> 2) & 1);
    const int DW = (l31 & 3) + 4 * (l31 >> 3);
    const float* wsrc = W + (size_t)i0 * 8192 + ((cW * 16 + DW) * 16 + h * 8);

    if (USE_V) {
        // stage v (i-invariant) once: slot = b*128 + (cd ^ (b&31)), float4 units
        const float4* v4 = (const float4*)vg;
        #pragma unroll
        for (int k = 0; k < 8; ++k) {
            int idx = k * 1024 + tid;
            int b = idx >> 7, cd = idx & 127;
            vt[b * 128 + (cd ^ (b & 31))] = v4[idx];
        }
        __syncthreads();
    }

    f32x16 s0, s1;
    #pragma unroll
    for (int q = 0; q < 16; ++q) { s0[q] = 0.f; s1[q] = 0.f; }

    for (int ii = 0; ii < IPB; ++ii) {
        const int i = i0 + ii;
        // ---- B fragments (3 terms x 2 n-tiles), direct global (L1/L3-hot)
        const unsigned short* bb = Xp + (size_t)i * 1024 + (size_t)h * 512 + l31 * 8;
        uint4 b10 = *(const uint4*)(bb);
        uint4 b11 = *(const uint4*)(bb + 256);
        uint4 b20 = *(const uint4*)(bb + 4194304);
        uint4 b21 = *(const uint4*)(bb + 4194304 + 256);
        uint4 b30 = *(const uint4*)(bb + 8388608);
        uint4 b31 = *(const uint4*)(bb + 8388608 + 256);

        // ---- A fragments: load 8 fp32 weights, split to 3 bf16 planes in-reg
        const float4* w4 = (const float4*)(wsrc + (size_t)ii * 8192);
        float4 wa = w4[0], wb = w4[1];
        uint4 a1, a2, a3;
        a1.x = split3(wa.x, wa.y, a2.x, a3.x);
        a1.y = split3(wa.z, wa.w, a2.y, a3.y);
        a1.z = split3(wb.x, wb.y, a2.z, a3.z);
        a1.w = split3(wb.z, wb.w, a2.w, a3.w);

        #define MF(A_, B_, C_) __builtin_amdgcn_mfma_f32_32x32x16_bf16( \
            __builtin_bit_cast(bf16x8, A_), __builtin_bit_cast(bf16x8, B_), C_, 0, 0, 0)

        if (USE_V == 0) {
            // pure accumulate: s += W.x  (6 terms, 2 n-tiles, interleaved chains)
            s0 = MF(a1, b10, s0); s1 = MF(a1, b11, s1);
            s0 = MF(a2, b10, s0); s1 = MF(a2, b11, s1);
            s0 = MF(a1, b20, s0); s1 = MF(a1, b21, s1);
            s0 = MF(a3, b10, s0); s1 = MF(a3, b11, s1);
            s0 = MF(a2, b20, s0); s1 = MF(a2, b21, s1);
            s0 = MF(a1, b30, s0); s1 = MF(a1, b31, s1);
        } else {
            f32x16 u0, u1;
            #pragma unroll
            for (int q = 0; q < 16; ++q) { u0[q] = 0.f; u1[q] = 0.f; }
            u0 = MF(a1, b10, u0); u1 = MF(a1, b11, u1);
            u0 = MF(a2, b10, u0); u1 = MF(a2, b11, u1);
            u0 = MF(a1, b20, u0); u1 = MF(a1, b21, u1);
            u0 = MF(a3, b10, u0); u1 = MF(a3, b11, u1);
            u0 = MF(a2, b20, u0); u1 = MF(a2, b21, u1);
            u0 = MF(a1, b30, u0); u1 = MF(a1, b31, u1);

            // ---- p = sum_D u*v  (full D per lane; reg q == D)
            #pragma unroll
            for (int nt = 0; nt < 2; ++nt) {
                const f32x16& uu = nt ? u1 : u0;
                const int b = nt * 32 + l31;
                float p = 0.f;
                #pragma unroll
                for (int dblk = 0; dblk < 4; ++dblk) {
                    float4 vv = vt[b * 128 + ((cA * 4 + dblk) ^ l31)];
                    p = fmaf(uu[dblk * 4 + 0], vv.x, p);
                    p = fmaf(uu[dblk * 4 + 1], vv.y, p);
                    p = fmaf(uu[dblk * 4 + 2], vv.z, p);
                    p = fmaf(uu[dblk * 4 + 3], vv.w, p);
                }
                p_lds[cA * 65 + b] = p;
            }
            __syncthreads();
            // ---- softmax over c: wave mt owns b = mt*4 + r*2 + h; lanes = c
            #pragma unroll
            for (int r2 = 0; r2 < 2; ++r2) {
                const int b = mt * 4 + r2 * 2 + h;
                float e = __expf(p_lds[l31 * 65 + b]);   // |p| bounded, no max-sub
                float t = e;
                t += __shfl_xor(t, 16); t += __shfl_xor(t, 8);
                t += __shfl_xor(t, 4);  t += __shfl_xor(t, 2);
                t += __shfl_xor(t, 1);
                cij_lds[l31 * 65 + b] = __fdividef(e, t);
            }
            __syncthreads();
            // ---- s += cij * u
            #pragma unroll
            for (int nt = 0; nt < 2; ++nt) {
                const f32x16& uu = nt ? u1 : u0;
                f32x16&       ss = nt ? s1 : s0;
                const int b = nt * 32 + l31;
                const float cij = cij_lds[cA * 65 + b];
                #pragma unroll
                for (int q = 0; q < 16; ++q) ss[q] = fmaf(cij, uu[q], ss[q]);
            }
        }
        #undef MF
    }

    // ---- slab[itile][b][c][D] partial write
    float4* slab4 = (float4*)slab;
    #pragma unroll
    for (int nt = 0; nt < 2; ++nt) {
        const f32x16& ss = nt ? s1 : s0;
        const int b = nt * 32 + l31;
        size_t base = ((size_t)itile * 64 + b) * 128 + cA * 4;
        #pragma unroll
        for (int dblk = 0; dblk < 4; ++dblk) {
            float4 o = {ss[dblk * 4 + 0], ss[dblk * 4 + 1], ss[dblk * 4 + 2], ss[dblk * 4 + 3]};
            slab4[base + dblk] = o;
        }
    }
}

// ---------------------------------------------------------------------------
// Reduce 256 slabs -> s_j[b,c,D], squash -> out; optional v12 = out + v1in.
// ---------------------------------------------------------------------------
__global__ __launch_bounds__(256)
void reduce_squash(const float* __restrict__ slab, float* __restrict__ out, float scale,
                   const float* __restrict__ v1in, float* __restrict__ vsum)
{
    const int o = blockIdx.x * 256 + threadIdx.x;   // o = b*512 + c*16 + D
    float a[16];
    #pragma unroll
    for (int k = 0; k < 16; ++k) a[k] = 0.f;
    for (int g = 0; g < 16; ++g) {
        #pragma unroll
        for (int k = 0; k < 16; ++k)
            a[k] += slab[(size_t)(g * 16 + k) * 32768 + o];
    }
    float s = 0.f;
    #pragma unroll
    for (int k = 0; k < 16; ++k) s += a[k];
    s *= scale;
    float t = s * s;
    t += __shfl_xor(t, 1);
    t += __shfl_xor(t, 2);
    t += __shfl_xor(t, 4);
    t += __shfl_xor(t, 8);
    float r = s / (1.0f + t) / sqrtf(t + 1e-9f);
    out[o] = r;
    if (v1in) vsum[o] = r + v1in[o];
}

extern "C" void kernel_launch(void* const* d_in, const int* in_sizes, int n_in,
                              void* d_out, int out_size, void* d_ws, size_t ws_size,
                              hipStream_t stream)
{
    const float* x = (const float*)d_in[0];   // [64, 4096, 16]
    const float* W = (const float*)d_in[1];   // [1, 4096, 32, 16, 16]

    // workspace: slab 32MB | v1,v2,v12 384KB | Xp 24MB bf16x3  (no Wp anymore)
    float* slab = (float*)d_ws;
    float* v1   = slab + (size_t)ITILES * 32768;
    float* v2   = v1 + 32768;
    float* v12  = v2 + 32768;
    unsigned short* Xp = (unsigned short*)(v12 + 32768);
    float* out  = (float*)d_out;

    hipLaunchKernelGGL(prep_x, dim3(4096), dim3(128), 0, stream, x, Xp);

    // iter 1: uniform c (1/32 folded into reduce scale)
    hipLaunchKernelGGL((pass_kernel<0>), dim3(ITILES), dim3(1024), 0, stream, W, Xp, (const float*)nullptr, slab);
    hipLaunchKernelGGL(reduce_squash,    dim3(128),    dim3(256),  0, stream, slab, v1, 1.0f / 32.0f, (const float*)nullptr, (float*)nullptr);
    // iter 2: p = u.v1 ; reduce also emits v12 = v1 + v2
    hipLaunchKernelGGL((pass_kernel<1>), dim3(ITILES), dim3(1024), 0, stream, W, Xp, v1, slab);
    hipLaunchKernelGGL(reduce_squash,    dim3(128),    dim3(256),  0, stream, slab, v2, 1.0f, v1, v12);
    // iter 3: p = u.(v1+v2) = u.v12
    hipLaunchKernelGGL((pass_kernel<1>), dim3(ITILES), dim3(1024), 0, stream, W, Xp, v12, slab);
    hipLaunchKernelGGL(reduce_squash,    dim3(128),    dim3(256),  0, stream, slab, out, 1.0f, (const float*)nullptr, (float*)nullptr);
}